// Round 2
// baseline (346.812 us; speedup 1.0000x reference)
//
#include <hip/hip_runtime.h>
#include <math.h>

#define PI_F 3.14159265358979323846f

// ---------------- main kernel ----------------
// LDS plane: 128 rows x 32 float4 blocks = exactly 64 KB. Reads are
// lane-contiguous per row (conflict-free; the two half-wave rows alias banks
// only 2-way, which is free). OOB handled by value-masking.
// No d_ws use anywhere: per-(o,t) shift+weights are computed redundantly
// per wave (lane t = lane&15 owns tap t) and broadcast via v_readlane.

__device__ __forceinline__ void rd8(float (&D)[8], const float4* __restrict__ L,
                                    int row, int b0, bool vb0, bool vb1) {
  bool vr = ((unsigned)row) < 128u;
  int base = row * 32;
  bool v0 = vr & vb0;
  bool v1 = vr & vb1;
  int i0 = v0 ? (base + b0) : 0;
  int i1 = v1 ? (base + b0 + 1) : 0;
  float4 q0 = L[i0];
  float4 q1 = L[i1];
  if (!v0) { q0.x = 0.f; q0.y = 0.f; q0.z = 0.f; q0.w = 0.f; }
  if (!v1) { q1.x = 0.f; q1.y = 0.f; q1.z = 0.f; q1.w = 0.f; }
  D[0] = q0.x; D[1] = q0.y; D[2] = q0.z; D[3] = q0.w;
  D[4] = q1.x; D[5] = q1.y; D[6] = q1.z; D[7] = q1.w;
}

template <int R>
__device__ __forceinline__ void tap4(float4& a, const float (&T)[8], const float (&B)[8],
                                     float w00, float w01, float w10, float w11) {
  a.x = fmaf(w00, T[R + 0], fmaf(w01, T[R + 1], fmaf(w10, B[R + 0], fmaf(w11, B[R + 1], a.x))));
  a.y = fmaf(w00, T[R + 1], fmaf(w01, T[R + 2], fmaf(w10, B[R + 1], fmaf(w11, B[R + 2], a.y))));
  a.z = fmaf(w00, T[R + 2], fmaf(w01, T[R + 3], fmaf(w10, B[R + 2], fmaf(w11, B[R + 3], a.z))));
  a.w = fmaf(w00, T[R + 3], fmaf(w01, T[R + 4], fmaf(w10, B[R + 3], fmaf(w11, B[R + 4], a.w))));
}

template <int R>
__device__ __forceinline__ void kloop(float4 (&acc)[8], const float4* __restrict__ L,
                                      int rowT, int b0, bool vb0, bool vb1,
                                      float w00, float w01, float w10, float w11) {
  float A[8], Bf[8];
  rd8(A, L, rowT, b0, vb0, vb1);  // top row for k=0
  int row = rowT + 1;
#pragma unroll
  for (int kk = 0; kk < 4; kk++) {
    rd8(Bf, L, row, b0, vb0, vb1);
    tap4<R>(acc[2 * kk + 0], A, Bf, w00, w01, w10, w11);
    row++;
    rd8(A, L, row, b0, vb0, vb1);
    tap4<R>(acc[2 * kk + 1], Bf, A, w00, w01, w10, w11);
    row++;
  }
}

__global__ __launch_bounds__(512, 4)
void pgd_main_kernel(const float* __restrict__ X,
                     const float* __restrict__ offx, const float* __restrict__ offy,
                     const float* __restrict__ ua, const float* __restrict__ us,
                     const float* __restrict__ araw, const float* __restrict__ sraw,
                     float* __restrict__ out) {
  __shared__ float4 L[4096];  // 64 KB: one 128x128 plane
  int p = blockIdx.x;         // plane = b*128 + o*4 + c
  int o = (p & 127) >> 2;
  const float4* __restrict__ xg = (const float4*)(X + (size_t)p * 16384);
  int tid = threadIdx.x;

#pragma unroll
  for (int i = 0; i < 8; i++) L[tid + i * 512] = xg[tid + i * 512];

  // ---- per-wave tap params (overlaps with staging loads) ----
  int lane = tid & 63;
  int t = lane & 15;
  const float MIN_A = 0.024979197860971382f;   // atan2(0.5,10)/2
  const float MAX_A = PI_F;
  const float MIN_S = 0.2f, MAX_S = 5.0f;
  const float EPS = 1.1920928955078125e-07f;   // np.float32 eps

  float angle_std = 1.0f / (1.0f + expf(-araw[o])) * (MAX_A - MIN_A) + MIN_A;
  float scale_std = 1.0f / (1.0f + expf(-sraw[o])) * (MAX_S - MIN_S) + MIN_S;
  float high_a = fminf(angle_std * 3.0f, PI_F);
  float s3 = scale_std * 3.0f;
  float va = angle_std * angle_std + EPS;
  float vs = scale_std * scale_std + EPS;

  float denom = 0.0f;
  for (int j = 0; j < 32; j++) {
    float a = ua[o * 32 + j] * high_a;
    float s = us[o * 32 + j] * s3;
    denom += expf(-(a * a) * 0.5f / va - (s * s) * 0.5f / vs);
  }
  denom += EPS;

  float a_t = ua[o * 32 + t] * high_a;
  float s_t = us[o * 32 + t] * s3;
  float wt = expf(-(a_t * a_t) * 0.5f / va - (s_t * s_t) * 0.5f / vs) / denom * 2.0f;

  float oxv = offx[o], oyv = offy[o];
  float dist = sqrtf(oxv * oxv + oyv * oyv);
  float ang0 = atan2f(oyv, oxv);
  float ndv = dist + s_t;
  float nav = ang0 + a_t;
  float dxv = ndv * cosf(nav);
  float dyv = ndv * sinf(nav);
  float fxv = floorf(dxv), fyv = floorf(dyv);
  float axv = dxv - fxv, ayv = dyv - fyv;
  int ixL = (int)fxv;   // exact: fxv already floored
  int iyL = (int)fyv;
  float w00L = wt * (1.0f - ayv) * (1.0f - axv);
  float w01L = wt * (1.0f - ayv) * axv;
  float w10L = wt * ayv * (1.0f - axv);
  float w11L = wt * ayv * axv;

  __syncthreads();

  int wv = tid >> 6;        // 0..7
  int half = lane >> 5;     // 0..1
  int c = lane & 31;        // float4 output chunk: cols 4c..4c+3
  int g = wv * 2 + half;    // row-group 0..15
  int y0 = g * 8;           // 8 output rows y0..y0+7
  float* outp = out + (size_t)p * 16384;

  float4 acc[8];
#pragma unroll
  for (int k = 0; k < 8; k++) acc[k] = make_float4(0.f, 0.f, 0.f, 0.f);

  for (int tt = 0; tt < 16; tt++) {
    // broadcast tap tt's params from lane tt (wave-uniform -> SGPRs)
    float w00 = __uint_as_float(__builtin_amdgcn_readlane(__float_as_uint(w00L), tt));
    float w01 = __uint_as_float(__builtin_amdgcn_readlane(__float_as_uint(w01L), tt));
    float w10 = __uint_as_float(__builtin_amdgcn_readlane(__float_as_uint(w10L), tt));
    float w11 = __uint_as_float(__builtin_amdgcn_readlane(__float_as_uint(w11L), tt));
    int ix = __builtin_amdgcn_readlane(ixL, tt);
    int iy = __builtin_amdgcn_readlane(iyL, tt);

    int s0 = 4 * c + ix;      // leftmost needed input col
    int b0 = s0 >> 2;         // arithmetic shift = floor div 4
    int r = ix & 3;           // wave-uniform sub-word alignment
    bool vb0 = ((unsigned)b0) < 32u;
    bool vb1 = ((unsigned)(b0 + 1)) < 32u;
    int rowT = y0 + iy;       // top input row for k=0

    switch (r) {
      case 0: kloop<0>(acc, L, rowT, b0, vb0, vb1, w00, w01, w10, w11); break;
      case 1: kloop<1>(acc, L, rowT, b0, vb0, vb1, w00, w01, w10, w11); break;
      case 2: kloop<2>(acc, L, rowT, b0, vb0, vb1, w00, w01, w10, w11); break;
      default: kloop<3>(acc, L, rowT, b0, vb0, vb1, w00, w01, w10, w11); break;
    }
  }

#pragma unroll
  for (int k = 0; k < 8; k++) {
    *(float4*)(outp + (size_t)(y0 + k) * 128 + 4 * c) = acc[k];
  }
}

extern "C" void kernel_launch(void* const* d_in, const int* in_sizes, int n_in,
                              void* d_out, int out_size, void* d_ws, size_t ws_size,
                              hipStream_t stream) {
  const float* x  = (const float*)d_in[0];
  const float* ox = (const float*)d_in[1];
  const float* oy = (const float*)d_in[2];
  const float* ua = (const float*)d_in[3];
  const float* us = (const float*)d_in[4];
  const float* ar = (const float*)d_in[5];
  const float* sr = (const float*)d_in[6];
  float* out = (float*)d_out;
  (void)d_ws; (void)ws_size; (void)in_sizes; (void)n_in; (void)out_size;

  hipLaunchKernelGGL(pgd_main_kernel, dim3(2048), dim3(512), 0, stream,
                     x, ox, oy, ua, us, ar, sr, out);
}